// Round 1
// baseline (9207.350 us; speedup 1.0000x reference)
//
#include <hip/hip_runtime.h>
#include <hip/hip_bf16.h>
#include <math.h>

#define S_ 64
#define B_ 64
#define H_ 512
#define E_ 512
#define L_ 2
#define V_ 32000

#define SB_   (S_*B_)        // 4096
#define SBE_  (S_*B_*E_)     // 2097152
#define SBH_  (S_*B_*H_)     // 2097152
#define BH_   (B_*H_)        // 32768

// ---------------------------------------------------------------------------
// Embedding gather: x[s,b,:] = emb[tokens[s,b],:]   (float4 vectorized)
// grid = S*B*(E/4)/256 = 2048 blocks
// ---------------------------------------------------------------------------
__global__ __launch_bounds__(256) void embed_k(const int* __restrict__ tok,
                                               const float* __restrict__ emb,
                                               float* __restrict__ x) {
    int idx = blockIdx.x * 256 + threadIdx.x;   // over S*B*(E/4)
    int e4 = idx & (E_/4 - 1);                  // 128 float4 per row
    int sb = idx >> 7;
    int tk = tok[sb];
    *(float4*)(x + (size_t)sb * E_ + e4 * 4) =
        *(const float4*)(emb + (size_t)tk * E_ + e4 * 4);
}

// ---------------------------------------------------------------------------
// Generic fp32 GEMM + bias: C[M,N] = A[M,K] @ W[K,N] + bias[N]
// Tile 64x64, 256 threads, 4x4 per thread, KT=16.
// grid = dim3(N/64, M/64)
// ---------------------------------------------------------------------------
__global__ __launch_bounds__(256) void gemm_bias(
    const float* __restrict__ A, int lda,
    const float* __restrict__ W, int ldw,
    const float* __restrict__ bias,
    float* __restrict__ C, int ldc,
    int K) {
    __shared__ float As[16][68];   // transposed: As[k][m]
    __shared__ float Bs[16][68];   // Bs[k][n]

    const int tid = threadIdx.x;
    const int tx = tid & 15;       // n-tile lane
    const int ty = tid >> 4;       // m-tile lane
    const int n0 = blockIdx.x * 64;
    const int m0 = blockIdx.y * 64;

    float acc[4][4] = {};

    for (int k0 = 0; k0 < K; k0 += 16) {
        // stage A tile [64 rows x 16 k] -> As[k][m]
        {
            int i  = tid >> 2;      // row 0..63
            int j4 = tid & 3;       // which float4 of the 16 k's
            const float4 av = *(const float4*)(A + (size_t)(m0 + i) * lda + k0 + j4 * 4);
            As[j4 * 4 + 0][i] = av.x;
            As[j4 * 4 + 1][i] = av.y;
            As[j4 * 4 + 2][i] = av.z;
            As[j4 * 4 + 3][i] = av.w;
        }
        // stage B tile [16 k x 64 n]
        {
            int r  = tid >> 4;      // k 0..15
            int c4 = tid & 15;      // float4 col
            *(float4*)(&Bs[r][c4 * 4]) =
                *(const float4*)(W + (size_t)(k0 + r) * ldw + n0 + c4 * 4);
        }
        __syncthreads();
        #pragma unroll
        for (int kk = 0; kk < 16; kk++) {
            float4 a4 = *(float4*)(&As[kk][ty * 4]);
            float4 b4 = *(float4*)(&Bs[kk][tx * 4]);
            acc[0][0] += a4.x * b4.x; acc[0][1] += a4.x * b4.y; acc[0][2] += a4.x * b4.z; acc[0][3] += a4.x * b4.w;
            acc[1][0] += a4.y * b4.x; acc[1][1] += a4.y * b4.y; acc[1][2] += a4.y * b4.z; acc[1][3] += a4.y * b4.w;
            acc[2][0] += a4.z * b4.x; acc[2][1] += a4.z * b4.y; acc[2][2] += a4.z * b4.z; acc[2][3] += a4.z * b4.w;
            acc[3][0] += a4.w * b4.x; acc[3][1] += a4.w * b4.y; acc[3][2] += a4.w * b4.z; acc[3][3] += a4.w * b4.w;
        }
        __syncthreads();
    }

    float4 bv = *(const float4*)(bias + n0 + tx * 4);
    #pragma unroll
    for (int i = 0; i < 4; i++) {
        int row = m0 + ty * 4 + i;
        float4 out;
        out.x = acc[i][0] + bv.x;
        out.y = acc[i][1] + bv.y;
        out.z = acc[i][2] + bv.z;
        out.w = acc[i][3] + bv.w;
        *(float4*)(C + (size_t)row * ldc + n0 + tx * 4) = out;
    }
}

// ---------------------------------------------------------------------------
// Per-step gate kernel: r and z gates.
//   pre_g[b,c] = P_g[b,c] + sum_k h_prev[b,k] * Wg_hid[k,c]
//   g==0 (r): rhbuf[b,c] = sigmoid(pre) * h_prev[b,c]
//   g==1 (z): zbuf[b,c]  = sigmoid(pre)
// grid = 64 blocks: g = bid>>5, column-tile (16 cols) = bid&31. 256 threads.
// thread: c = ct*16 + (tid&15); computes 4 batches (bg = tid>>4).
// ---------------------------------------------------------------------------
__device__ __forceinline__ float sigmoidf_(float xv) {
    float e = __expf(-fabsf(xv));
    float s = 1.f / (1.f + e);
    return xv >= 0.f ? s : 1.f - s;
}

__global__ __launch_bounds__(256) void rz_step(
    const float* __restrict__ Pr_t, const float* __restrict__ Pz_t,
    const float* __restrict__ Wr_hid, const float* __restrict__ Wz_hid,
    const float* __restrict__ h_prev,
    float* __restrict__ zbuf, float* __restrict__ rhbuf) {
    __shared__ float hs[64][132];   // pad 132 (mult of 4): float4-aligned rows, 2-way max bank alias
    const int bid = blockIdx.x;
    const int g = bid >> 5;
    const int ct = bid & 31;
    const int tid = threadIdx.x;
    const int c = ct * 16 + (tid & 15);
    const int bg = tid >> 4;        // 0..15 -> 4 batches each

    const float* Wg = g ? Wz_hid : Wr_hid;
    const float* P  = g ? Pz_t   : Pr_t;

    float acc[4] = {0.f, 0.f, 0.f, 0.f};

    for (int kk = 0; kk < H_; kk += 128) {
        // stage h_prev[:, kk:kk+128] into LDS
        #pragma unroll
        for (int q = 0; q < 8; q++) {
            int idx = q * 256 + tid;        // 0..2047
            int row = idx >> 5;             // 32 float4 per row
            int c4  = idx & 31;
            *(float4*)(&hs[row][c4 * 4]) =
                *(const float4*)(h_prev + row * H_ + kk + c4 * 4);
        }
        __syncthreads();
        const float* Wp = Wg + (size_t)kk * H_ + c;
        #pragma unroll 4
        for (int k = 0; k < 128; k++) {
            float w = Wp[(size_t)k * H_];
            #pragma unroll
            for (int i = 0; i < 4; i++)
                acc[i] += w * hs[bg * 4 + i][k];
        }
        __syncthreads();
    }

    #pragma unroll
    for (int i = 0; i < 4; i++) {
        int b = bg * 4 + i;
        float pre = P[b * H_ + c] + acc[i];
        float v = sigmoidf_(pre);
        if (g == 0) rhbuf[b * H_ + c] = v * h_prev[b * H_ + c];
        else        zbuf[b * H_ + c]  = v;
    }
}

// ---------------------------------------------------------------------------
// Per-step candidate + update kernel.
//   hh = tanh(Ph[b,c] + sum_k rh[b,k] * Wh_hid[k,c])
//   h_out[b,c] = (1-z)*h_prev + z*hh
// grid = 32 blocks (column tiles of 16), 256 threads.
// ---------------------------------------------------------------------------
__global__ __launch_bounds__(256) void hh_step(
    const float* __restrict__ Ph_t,
    const float* __restrict__ Wh_hid,
    const float* __restrict__ rh,
    const float* __restrict__ h_prev,
    const float* __restrict__ zbuf,
    float* __restrict__ h_out) {
    __shared__ float hs[64][132];
    const int ct = blockIdx.x;
    const int tid = threadIdx.x;
    const int c = ct * 16 + (tid & 15);
    const int bg = tid >> 4;

    float acc[4] = {0.f, 0.f, 0.f, 0.f};

    for (int kk = 0; kk < H_; kk += 128) {
        #pragma unroll
        for (int q = 0; q < 8; q++) {
            int idx = q * 256 + tid;
            int row = idx >> 5;
            int c4  = idx & 31;
            *(float4*)(&hs[row][c4 * 4]) =
                *(const float4*)(rh + row * H_ + kk + c4 * 4);
        }
        __syncthreads();
        const float* Wp = Wh_hid + (size_t)kk * H_ + c;
        #pragma unroll 4
        for (int k = 0; k < 128; k++) {
            float w = Wp[(size_t)k * H_];
            #pragma unroll
            for (int i = 0; i < 4; i++)
                acc[i] += w * hs[bg * 4 + i][k];
        }
        __syncthreads();
    }

    #pragma unroll
    for (int i = 0; i < 4; i++) {
        int b = bg * 4 + i;
        float pre = Ph_t[b * H_ + c] + acc[i];
        float hhv = tanhf(pre);
        float z = zbuf[b * H_ + c];
        float h = h_prev[b * H_ + c];
        h_out[b * H_ + c] = (1.f - z) * h + z * hhv;
    }
}

// ---------------------------------------------------------------------------
extern "C" void kernel_launch(void* const* d_in, const int* in_sizes, int n_in,
                              void* d_out, int out_size, void* d_ws, size_t ws_size,
                              hipStream_t stream) {
    const int*   tokens = (const int*)  d_in[0];
    const float* hidden = (const float*)d_in[1];   // [L,B,H] zeros
    const float* emb    = (const float*)d_in[2];   // [V,E]
    const float* Wr     = (const float*)d_in[3];   // [L,E+H,H]
    const float* br     = (const float*)d_in[4];   // [L,H]
    const float* Wz     = (const float*)d_in[5];
    const float* bz     = (const float*)d_in[6];
    const float* Wh     = (const float*)d_in[7];
    const float* bh     = (const float*)d_in[8];
    const float* Wout   = (const float*)d_in[9];   // [H,V]
    const float* bout   = (const float*)d_in[10];  // [V]

    float* out = (float*)d_out;            // logits [S,B,V] then hidden [L,B,H]
    float* out_hidden = out + (size_t)SB_ * V_;

    // workspace layout
    float* ws = (float*)d_ws;
    float* x     = ws;                 // SBE_
    float* hseq1 = x + SBE_;           // SBH_
    float* hseq2 = hseq1 + SBH_;       // SBH_
    float* Pr    = hseq2 + SBH_;       // SBH_
    float* Pz    = Pr + SBH_;          // SBH_
    float* Ph    = Pz + SBH_;          // SBH_
    float* zbuf  = Ph + SBH_;          // BH_
    float* rhbuf = zbuf + BH_;         // BH_

    // 1. embedding
    embed_k<<<SBE_ / 4 / 256, 256, 0, stream>>>(tokens, emb, x);

    const int WL = (E_ + H_) * H_;     // per-layer weight matrix size
    const float* layer_in[2] = {x, hseq1};
    float* hseqs[2] = {hseq1, hseq2};

    for (int l = 0; l < L_; l++) {
        const float* A = layer_in[l];
        const float* Wr_l = Wr + (size_t)l * WL;
        const float* Wz_l = Wz + (size_t)l * WL;
        const float* Wh_l = Wh + (size_t)l * WL;

        // 2. precompute input-side contributions for all timesteps:
        //    P_g = A @ Wg[0:E,:] + b_g      (A is [S*B, 512])
        dim3 gpre(H_ / 64, SB_ / 64);
        gemm_bias<<<gpre, 256, 0, stream>>>(A, E_, Wr_l, H_, br + l * H_, Pr, H_, E_);
        gemm_bias<<<gpre, 256, 0, stream>>>(A, E_, Wz_l, H_, bz + l * H_, Pz, H_, E_);
        gemm_bias<<<gpre, 256, 0, stream>>>(A, E_, Wh_l, H_, bh + l * H_, Ph, H_, E_);

        const float* Wr_hid = Wr_l + (size_t)E_ * H_;
        const float* Wz_hid = Wz_l + (size_t)E_ * H_;
        const float* Wh_hid = Wh_l + (size_t)E_ * H_;

        // 3. sequential recurrence over timesteps
        for (int t = 0; t < S_; t++) {
            const float* h_prev = (t == 0) ? (hidden + (size_t)l * BH_)
                                           : (hseqs[l] + (size_t)(t - 1) * BH_);
            rz_step<<<64, 256, 0, stream>>>(Pr + (size_t)t * BH_, Pz + (size_t)t * BH_,
                                            Wr_hid, Wz_hid, h_prev, zbuf, rhbuf);
            hh_step<<<32, 256, 0, stream>>>(Ph + (size_t)t * BH_, Wh_hid, rhbuf,
                                            h_prev, zbuf, hseqs[l] + (size_t)t * BH_);
        }

        // 4. final hidden state for this layer
        hipMemcpyAsync(out_hidden + (size_t)l * BH_, hseqs[l] + (size_t)(S_ - 1) * BH_,
                       (size_t)BH_ * sizeof(float), hipMemcpyDeviceToDevice, stream);
    }

    // 5. logits = hseq2 @ Wout + bout   -> [4096, 32000]
    dim3 glog(V_ / 64, SB_ / 64);
    gemm_bias<<<glog, 256, 0, stream>>>(hseq2, H_, Wout, V_, bout, out, V_, H_);
}